// Round 10
// baseline (372.683 us; speedup 1.0000x reference)
//
#include <hip/hip_runtime.h>
#include <hip/hip_bf16.h>
#include <math.h>

// ---------------------------------------------------------------------------
// Round 15: cut 2 launches via pure data-flow (no cross-block sync).
//   - r11/r13 proved cross-workgroup sync idioms regress badly on 8-XCD
//     MI355X; launch gaps (~155us over 11 enqueues) attacked differently:
//   - memset fusion: transpose tail blocks zero A's mirror blocks + dead
//     rows themselves -> hipMemsetAsync enqueue removed.
//   - reduce8_bias absorbed into reduce_prod: Hb was only consumed there;
//     sum the 8 PartL2 z-partials + bias inline (identical fp order).
//     reduce8 launch + 4MB Hb round-trip removed.
//   - Everything else identical to r14 (332.2us measured).
// ---------------------------------------------------------------------------

typedef __attribute__((ext_vector_type(8))) short short8;
typedef __attribute__((ext_vector_type(4))) float floatx4;

#define AS1 __attribute__((address_space(1)))
#define AS3 __attribute__((address_space(3)))
#define GLD16(g, l) __builtin_amdgcn_global_load_lds((AS1 const unsigned int*)(g), (AS3 unsigned int*)(l), 16, 0, 0)

__device__ __forceinline__ float silu_f(float x) {
    return x / (1.0f + __expf(-x));
}

// RNE split of fp32 into two bf16 (hi + lo)
__device__ __forceinline__ void split2(float x, unsigned short& hi, unsigned short& lo) {
    unsigned u = __float_as_uint(x);
    unsigned r = u + 0x7FFFu + ((u >> 16) & 1u);
    unsigned short h = (unsigned short)(r >> 16);
    float hf = __uint_as_float((unsigned)h << 16);
    float rem = x - hf;
    unsigned u2 = __float_as_uint(rem);
    unsigned r2 = u2 + 0x7FFFu + ((u2 >> 16) & 1u);
    hi = h;
    lo = (unsigned short)(r2 >> 16);
}

// ---------------- transpose + split, 64x64 tiles + A-build tail ------------
// W[K][N] f32 -> Th[N][K], Tl[N][K] bf16 (k-contiguous). nt reads.
// Tail blocks: h_one (32x1024) -> block-diagonal A[128][2048] hi/lo,
// including all zero regions (mirror blocks + dead rows 32-63 / 96-127).
__global__ __launch_bounds__(256)
void transpose_split_all(const float* __restrict__ w10, const float* __restrict__ w11,
                         const float* __restrict__ w12, const float* __restrict__ h_one,
                         unsigned short* __restrict__ t10h, unsigned short* __restrict__ t10l,
                         unsigned short* __restrict__ t11h, unsigned short* __restrict__ t11l,
                         unsigned short* __restrict__ t12h, unsigned short* __restrict__ t12l,
                         unsigned short* __restrict__ Ah, unsigned short* __restrict__ Al) {
    const int t = threadIdx.x;
    int id = blockIdx.x;

    if (id >= 8192) {
        // A-build tail: 8 blocks x 4096 elements (h_one = 32x1024)
        const int tb = id - 8192;
        const int base = tb * 4096 + t * 16;
        const ushort4 zz = {0, 0, 0, 0};
        #pragma unroll
        for (int j = 0; j < 4; ++j) {
            const int f = base + 4 * j;
            const int r = f >> 10;
            const int c = f & 1023;
            floatx4 v = __builtin_nontemporal_load((const floatx4*)&h_one[f]);
            ushort4 hv, lv;
            split2(v.x, hv.x, lv.x);
            split2(v.y, hv.y, lv.y);
            split2(v.z, hv.z, lv.z);
            split2(v.w, hv.w, lv.w);
            const size_t o1 = (size_t)r * 2048 + c;                 // [H | 0] row r
            const size_t o2 = (size_t)(64 + r) * 2048 + 1024 + c;   // [0 | H] row 64+r
            *(ushort4*)&Ah[o1] = hv;
            *(ushort4*)&Al[o1] = lv;
            *(ushort4*)&Ah[o2] = hv;
            *(ushort4*)&Al[o2] = lv;
            // zero mirrors (rows 0-31 cols 1024+, rows 64-95 cols 0-1023)
            const size_t z1 = (size_t)r * 2048 + 1024 + c;
            const size_t z2 = (size_t)(64 + r) * 2048 + c;
            *(ushort4*)&Ah[z1] = zz;
            *(ushort4*)&Al[z1] = zz;
            *(ushort4*)&Ah[z2] = zz;
            *(ushort4*)&Al[z2] = zz;
        }
        // zero dead rows 32..63 and 96..127 (each block slices 1/8 of 64K els)
        const unsigned off1 = 32 * 2048, off2 = 96 * 2048;
        #pragma unroll
        for (int q = 0; q < 8; ++q) {
            const unsigned e = (unsigned)tb * 8192 + (unsigned)(q * 256 + t) * 4;
            *(ushort4*)&Ah[off1 + e] = zz;
            *(ushort4*)&Al[off1 + e] = zz;
            *(ushort4*)&Ah[off2 + e] = zz;
            *(ushort4*)&Al[off2 + e] = zz;
        }
        return;
    }

    const float* W;
    unsigned short *Th, *Tl;
    int K, N, nt, kt;
    if (id < 2048)       { W = w10; Th = t10h; Tl = t10l; K = 2048; N = 4096; nt = id & 63; kt = id >> 6; }
    else if (id < 6144)  { id -= 2048; W = w11; Th = t11h; Tl = t11l; K = 4096; N = 4096; nt = id & 63; kt = id >> 6; }
    else                 { id -= 6144; W = w12; Th = t12h; Tl = t12l; K = 4096; N = 2048; nt = id & 31; kt = id >> 5; }

    __shared__ float tile[64][65];
    const int n0 = nt * 64;
    const int k0 = kt * 64;

    const int lrow = t >> 4;        // 0..15
    const int lcol = (t & 15) * 4;  // 0..60
    #pragma unroll
    for (int p = 0; p < 4; ++p) {
        const int r = p * 16 + lrow;
        floatx4 v = __builtin_nontemporal_load((const floatx4*)&W[(size_t)(k0 + r) * N + n0 + lcol]);
        tile[r][lcol + 0] = v.x;
        tile[r][lcol + 1] = v.y;
        tile[r][lcol + 2] = v.z;
        tile[r][lcol + 3] = v.w;
    }
    __syncthreads();

    const int srow0 = t >> 3;       // 0..31
    const int koff  = (t & 7) * 8;  // 0..56
    #pragma unroll
    for (int p = 0; p < 2; ++p) {
        const int sn = p * 32 + srow0;
        unsigned short hv[8], lv[8];
        #pragma unroll
        for (int kk = 0; kk < 8; ++kk)
            split2(tile[koff + kk][sn], hv[kk], lv[kk]);
        unsigned short* dh = &Th[(size_t)(n0 + sn) * K + k0 + koff];
        unsigned short* dl = &Tl[(size_t)(n0 + sn) * K + k0 + koff];
        *(short8*)dh = *(short8*)&hv[0];
        *(short8*)dl = *(short8*)&lv[0];
    }
}

// ---------------- m97-style LDS-staged GEMM, 128x128 tile ------------------
__global__ __launch_bounds__(256, 2)
void gemm128(const unsigned short* __restrict__ Ah, const unsigned short* __restrict__ Al,
             const unsigned short* __restrict__ Bh, const unsigned short* __restrict__ Bl,
             int K, float* __restrict__ Cpart, int N, int Mtot, int kc)
{
    __shared__ __align__(16) unsigned short As[2][128][32];
    __shared__ __align__(16) unsigned short Bs[2][128][32];

    const int tid  = threadIdx.x;
    const int lane = tid & 63;
    const int wid  = tid >> 6;
    const int n0 = blockIdx.x * 128;
    const int m0 = blockIdx.y * 128;
    const int kbase = blockIdx.z * kc;

    const int srow   = wid * 32 + (lane >> 2);
    const int schunk = (lane & 3) ^ ((srow >> 1) & 3);
    const unsigned short* gA0h = Ah + (size_t)(m0 + srow) * K + kbase + schunk * 8;
    const unsigned short* gA1h = gA0h + (size_t)16 * K;
    const unsigned short* gA0l = Al + (size_t)(m0 + srow) * K + kbase + schunk * 8;
    const unsigned short* gA1l = gA0l + (size_t)16 * K;
    const unsigned short* gB0h = Bh + (size_t)(n0 + srow) * K + kbase + schunk * 8;
    const unsigned short* gB1h = gB0h + (size_t)16 * K;
    const unsigned short* gB0l = Bl + (size_t)(n0 + srow) * K + kbase + schunk * 8;
    const unsigned short* gB1l = gB0l + (size_t)16 * K;
    unsigned short* lA0h = &As[0][wid * 32][0];
    unsigned short* lA1h = &As[0][wid * 32 + 16][0];
    unsigned short* lA0l = &As[1][wid * 32][0];
    unsigned short* lA1l = &As[1][wid * 32 + 16][0];
    unsigned short* lB0h = &Bs[0][wid * 32][0];
    unsigned short* lB1h = &Bs[0][wid * 32 + 16][0];
    unsigned short* lB0l = &Bs[1][wid * 32][0];
    unsigned short* lB1l = &Bs[1][wid * 32 + 16][0];

    const int mhalf = wid >> 1;
    const int nhalf = wid & 1;
    const int lm = lane & 15;
    const int q  = lane >> 4;
    int aoffs[4], boffs[4];
    #pragma unroll
    for (int f = 0; f < 4; ++f) {
        int arow = mhalf * 64 + f * 16 + lm;
        int aslot = q ^ ((arow >> 1) & 3);
        aoffs[f] = arow * 32 + aslot * 8;
        int brow = nhalf * 64 + f * 16 + lm;
        int bslot = q ^ ((brow >> 1) & 3);
        boffs[f] = brow * 32 + bslot * 8;
    }
    const unsigned short* AsF = &As[0][0][0];
    const unsigned short* BsF = &Bs[0][0][0];

    floatx4 acc[4][4];
    #pragma unroll
    for (int ms = 0; ms < 4; ++ms)
        #pragma unroll
        for (int ns = 0; ns < 4; ++ns)
            acc[ms][ns] = (floatx4){0.f, 0.f, 0.f, 0.f};

    const int S = kc >> 5;
    for (int s = 0; s < S; ++s) {
        const int ko = s << 5;
        __syncthreads();
        GLD16(gA0h + ko, lA0h);
        GLD16(gA1h + ko, lA1h);
        GLD16(gA0l + ko, lA0l);
        GLD16(gA1l + ko, lA1l);
        GLD16(gB0h + ko, lB0h);
        GLD16(gB1h + ko, lB1h);
        GLD16(gB0l + ko, lB0l);
        GLD16(gB1l + ko, lB1l);
        __syncthreads();

        short8 afh[4], afl[4], bfh[4], bfl[4];
        #pragma unroll
        for (int f = 0; f < 4; ++f) {
            afh[f] = *(const short8*)(AsF + aoffs[f]);
            afl[f] = *(const short8*)(AsF + 4096 + aoffs[f]);
            bfh[f] = *(const short8*)(BsF + boffs[f]);
            bfl[f] = *(const short8*)(BsF + 4096 + boffs[f]);
        }
        #pragma unroll
        for (int ms = 0; ms < 4; ++ms)
            #pragma unroll
            for (int ns = 0; ns < 4; ++ns)
                acc[ms][ns] = __builtin_amdgcn_mfma_f32_16x16x32_bf16(afh[ms], bfh[ns], acc[ms][ns], 0, 0, 0);
        #pragma unroll
        for (int ms = 0; ms < 4; ++ms)
            #pragma unroll
            for (int ns = 0; ns < 4; ++ns)
                acc[ms][ns] = __builtin_amdgcn_mfma_f32_16x16x32_bf16(afl[ms], bfh[ns], acc[ms][ns], 0, 0, 0);
        #pragma unroll
        for (int ms = 0; ms < 4; ++ms)
            #pragma unroll
            for (int ns = 0; ns < 4; ++ns)
                acc[ms][ns] = __builtin_amdgcn_mfma_f32_16x16x32_bf16(afh[ms], bfl[ns], acc[ms][ns], 0, 0, 0);
    }

    float* Cp = Cpart + (size_t)blockIdx.z * Mtot * N;
    const int lr = (lane >> 4) * 4;
    #pragma unroll
    for (int ms = 0; ms < 4; ++ms)
        #pragma unroll
        for (int ns = 0; ns < 4; ++ns)
            #pragma unroll
            for (int r = 0; r < 4; ++r)
                Cp[(size_t)(m0 + mhalf * 64 + ms * 16 + lr + r) * N + n0 + nhalf * 64 + ns * 16 + lm] = acc[ms][ns][r];
}

// ---------------- small kernels ----------------
// PQ = PartPQ[z][128][4096]: rows 0..63 P-chunks, rows 64..127 Q-chunks.
// grid (480, 4): x = pair row, y = column quarter.
__global__ __launch_bounds__(256)
void build_y1_kernel(const float* __restrict__ PQ, const float* __restrict__ b1,
                     unsigned short* __restrict__ Y1h, unsigned short* __restrict__ Y1l) {
    const int r = blockIdx.x;
    const int g = r / 240;
    const int rem = r % 240;
    const int o = rem / 120;
    const int p = rem % 120;
    int i = 0, pp = p, cnt = 15;
    while (pp >= cnt) { pp -= cnt; cnt--; i++; }
    const int j = i + 1 + pp;
    const int ai = g * 16 + (o ? j : i);
    const int bi = g * 16 + (o ? i : j);
    const size_t chunk4 = (size_t)128 * 4096 / 4;
    const float4* Pr0 = (const float4*)(PQ + (size_t)ai * 4096);
    const float4* Qr0 = (const float4*)(PQ + (size_t)(64 + bi) * 4096);
    const float4* Br  = (const float4*)b1;
    const int c = blockIdx.y * 256 + threadIdx.x;   // 0..1023 (float4 units)
    float4 bv = Br[c];
    float s0 = bv.x, s1 = bv.y, s2 = bv.z, s3 = bv.w;
    #pragma unroll
    for (int cc = 0; cc < 4; ++cc) {
        float4 pv = Pr0[c + cc * chunk4];
        float4 qv = Qr0[c + cc * chunk4];
        s0 += pv.x + qv.x;
        s1 += pv.y + qv.y;
        s2 += pv.z + qv.z;
        s3 += pv.w + qv.w;
    }
    s0 = silu_f(s0);
    s1 = silu_f(s1);
    s2 = silu_f(s2);
    s3 = silu_f(s3);
    ushort4 hv, lv;
    split2(s0, hv.x, lv.x);
    split2(s1, hv.y, lv.y);
    split2(s2, hv.z, lv.z);
    split2(s3, hv.w, lv.w);
    *(ushort4*)&Y1h[(size_t)r * 4096 + c * 4] = hv;
    *(ushort4*)&Y1l[(size_t)r * 4096 + c * 4] = lv;
}

__global__ __launch_bounds__(256)
void reduce4_silu_split(const float* __restrict__ Part, const float* __restrict__ bias,
                        unsigned short* __restrict__ Yh, unsigned short* __restrict__ Yl) {
    const size_t idx = (size_t)blockIdx.x * 256 + threadIdx.x;
    const size_t stride4 = (size_t)512 * 4096 / 4;
    const float4* p = (const float4*)Part;
    float4 v0 = p[idx], v1 = p[idx + stride4], v2 = p[idx + 2 * stride4], v3 = p[idx + 3 * stride4];
    const int col = (int)((idx * 4) & 4095);
    float4 b = *(const float4*)&bias[col];
    float s0 = silu_f(v0.x + v1.x + v2.x + v3.x + b.x);
    float s1 = silu_f(v0.y + v1.y + v2.y + v3.y + b.y);
    float s2 = silu_f(v0.z + v1.z + v2.z + v3.z + b.z);
    float s3 = silu_f(v0.w + v1.w + v2.w + v3.w + b.w);
    ushort4 hv, lv;
    split2(s0, hv.x, lv.x);
    split2(s1, hv.y, lv.y);
    split2(s2, hv.z, lv.z);
    split2(s3, hv.w, lv.w);
    *(ushort4*)&Yh[idx * 4] = hv;
    *(ushort4*)&Yl[idx * 4] = lv;
}

// grid (8,2,4): partial products of 30 pairs each -> a_part[(g*4+cz)][2048].
// Sums the 8 PartL2 z-partials + bias inline (replaces reduce8_bias+Hb):
// per-element fp order identical: z ascending, then +bias, then subtract.
__global__ __launch_bounds__(256)
void reduce_prod_kernel(const float* __restrict__ Part, const float* __restrict__ bias,
                        float* __restrict__ a_part) {
    const int g = blockIdx.y;
    const int cz = blockIdx.z;
    const int c = blockIdx.x * 256 + threadIdx.x;
    const float bv = bias[c];
    const size_t zs = (size_t)512 * 2048;
    float prod = 1.0f;
    const int p0 = cz * 30;
    for (int p = p0; p < p0 + 30; ++p) {
        const float* b1p = Part + (size_t)(g * 240 + p) * 2048 + c;
        const float* b2p = Part + (size_t)(g * 240 + 120 + p) * 2048 + c;
        float h1 = b1p[0];
        float h2 = b2p[0];
        #pragma unroll
        for (int z = 1; z < 8; ++z) {
            h1 += b1p[z * zs];
            h2 += b2p[z * zs];
        }
        prod *= (h1 + bv) - (h2 + bv);
    }
    a_part[(size_t)((g << 2) | cz) * 2048 + c] = prod;
}

// Part2[kc][g][n] = sum_{k in chunk kc} a[g][k] * W2_0[k][n]
// a[g][k] = prod of 4 partials. grid (8 nc, 16 kc).
__global__ __launch_bounds__(256)
void mlp2_acc2_kernel(const float* __restrict__ a_part, const float* __restrict__ W,
                      float* __restrict__ Part2) {
    __shared__ float a0s[128], a1s[128];
    const int kc = blockIdx.y, nc = blockIdx.x, t = threadIdx.x;
    if (t < 128) {
        const int k = kc * 128 + t;
        a0s[t] = a_part[k] * a_part[2048 + k] * a_part[4096 + k] * a_part[6144 + k];
        a1s[t] = a_part[8192 + k] * a_part[10240 + k] * a_part[12288 + k] * a_part[14336 + k];
    }
    __syncthreads();
    const int n = nc * 256 + t;
    const float* Wp = W + (size_t)(kc * 128) * 2048 + n;
    float s0 = 0.f, s1 = 0.f;
    #pragma unroll 8
    for (int kk = 0; kk < 128; ++kk) {
        float w = Wp[(size_t)kk * 2048];
        s0 = fmaf(a0s[kk], w, s0);
        s1 = fmaf(a1s[kk], w, s1);
    }
    Part2[kc * 4096 + n] = s0;
    Part2[kc * 4096 + 2048 + n] = s1;
}

__global__ __launch_bounds__(256)
void finalize_kernel(const float* __restrict__ Part2, const float* __restrict__ b2_0,
                     const float* __restrict__ w2_1, const float* __restrict__ b2_1,
                     float* __restrict__ out) {
    __shared__ float red[256];
    const int tid = threadIdx.x;
    float result = 0.0f;
    for (int g = 0; g < 2; ++g) {
        float s = 0.f;
        for (int n = tid; n < 2048; n += 256) {
            float acc = b2_0[n];
            #pragma unroll
            for (int kc = 0; kc < 16; ++kc)
                acc += Part2[kc * 4096 + g * 2048 + n];
            s += tanhf(acc) * w2_1[n];
        }
        red[tid] = s;
        __syncthreads();
        for (int off = 128; off > 0; off >>= 1) {
            if (tid < off) red[tid] += red[tid + off];
            __syncthreads();
        }
        if (tid == 0) result += logf(fabsf(red[0] + b2_1[0]));
        __syncthreads();
    }
    if (tid == 0) out[0] = result;
}

extern "C" void kernel_launch(void* const* d_in, const int* in_sizes, int n_in,
                              void* d_out, int out_size, void* d_ws, size_t ws_size,
                              hipStream_t stream) {
    const float* h_one = (const float*)d_in[0];
    const float* w1_0  = (const float*)d_in[1];
    const float* b1_0  = (const float*)d_in[2];
    const float* w1_1  = (const float*)d_in[3];
    const float* b1_1  = (const float*)d_in[4];
    const float* w1_2  = (const float*)d_in[5];
    const float* b1_2  = (const float*)d_in[6];
    const float* w2_0  = (const float*)d_in[7];
    const float* b2_0  = (const float*)d_in[8];
    const float* w2_1  = (const float*)d_in[9];
    const float* b2_1  = (const float*)d_in[10];
    float* out = (float*)d_out;

    char* ws = (char*)d_ws;
    // region0: W10t (33.5 MB), later PartL1 (4 x 512 x 4096 f32)
    unsigned short* W10t_h = (unsigned short*)ws;
    unsigned short* W10t_l = W10t_h + (size_t)4096 * 2048;
    float*          PartL1 = (float*)ws;
    ws += (size_t)4096 * 2048 * 2 * 2;
    // region1: W11t (67 MB), later PartL2 (8 x 512 x 2048 f32)
    unsigned short* W11t_h = (unsigned short*)ws;
    unsigned short* W11t_l = W11t_h + (size_t)4096 * 4096;
    float*          PartL2 = (float*)ws;
    ws += (size_t)4096 * 4096 * 2 * 2;
    // region2: W12t (33.5 MB), live through L2
    unsigned short* W12t_h = (unsigned short*)ws;
    unsigned short* W12t_l = W12t_h + (size_t)2048 * 4096;
    ws += (size_t)2048 * 4096 * 2 * 2;
    // block-diagonal A for PQ gemm: [128][2048] hi + lo (1 MB)
    unsigned short* Ah  = (unsigned short*)ws;  ws += (size_t)128 * 2048 * 2;
    unsigned short* Al  = (unsigned short*)ws;  ws += (size_t)128 * 2048 * 2;
    float* PQ  = (float*)ws;                    ws += (size_t)4 * 128 * 4096 * 4;
    unsigned short* Y1h = (unsigned short*)ws;  ws += (size_t)512 * 4096 * 2;
    unsigned short* Y1l = (unsigned short*)ws;  ws += (size_t)512 * 4096 * 2;
    unsigned short* Y2h = (unsigned short*)ws;  ws += (size_t)512 * 4096 * 2;
    unsigned short* Y2l = (unsigned short*)ws;  ws += (size_t)512 * 4096 * 2;
    float* a_part = (float*)ws;                 ws += (size_t)8 * 2048 * 4;
    float* Part2 = (float*)ws;                  ws += (size_t)16 * 2 * 2048 * 4;

    // weight transposes + A-build (incl. zeroing) — no memset needed
    transpose_split_all<<<8200, 256, 0, stream>>>(w1_0, w1_1, w1_2, h_one,
                                                  W10t_h, W10t_l, W11t_h, W11t_l,
                                                  W12t_h, W12t_l, Ah, Al);

    // PQ: one gemm128, M=128 (P rows 0..63, Q rows 64..127), N=4096, K=2048, Z=4
    gemm128<<<dim3(32, 1, 4), 256, 0, stream>>>(Ah, Al, W10t_h, W10t_l, 2048,
                                                PQ, 4096, 128, 512);
    build_y1_kernel<<<dim3(480, 4), 256, 0, stream>>>(PQ, b1_0, Y1h, Y1l);

    // L1: Y2 = silu(Y1 @ W1_1 + b1_1)  M=512 N=4096 K=4096, Z=4
    gemm128<<<dim3(32, 4, 4), 256, 0, stream>>>(Y1h, Y1l, W11t_h, W11t_l, 4096,
                                                PartL1, 4096, 512, 1024);
    reduce4_silu_split<<<2048, 256, 0, stream>>>(PartL1, b1_1, Y2h, Y2l);

    // L2: PartL2 = Y2 @ W1_2 (partials)  M=512 N=2048 K=4096, Z=8
    gemm128<<<dim3(16, 4, 8), 256, 0, stream>>>(Y2h, Y2l, W12t_h, W12t_l, 4096,
                                                PartL2, 2048, 512, 512);

    // tail: prod (sums 8 z-partials + bias inline), mlp2, finalize
    reduce_prod_kernel<<<dim3(8, 2, 4), 256, 0, stream>>>(PartL2, b1_2, a_part);
    mlp2_acc2_kernel<<<dim3(8, 16), 256, 0, stream>>>(a_part, w2_0, Part2);
    finalize_kernel<<<1, 256, 0, stream>>>(Part2, b2_0, w2_1, b2_1, out);
}

// Round 11
// 333.126 us; speedup vs baseline: 1.1187x; 1.1187x over previous
//
#include <hip/hip_runtime.h>
#include <hip/hip_bf16.h>
#include <math.h>

// ---------------------------------------------------------------------------
// Round 16: surgical revert of r15's reduce8->reduce_prod fusion (it moved a
// 1024-block BW-parallel z-sum into a 64-block latency-bound kernel re-reading
// 31.5MB: +40us). Restore reduce8_bias + Hb (r14 forms). KEEP the benign
// memset-fusion (A zeroing in transpose tail) and build_y1 grid split.
// Lesson: only remove a launch if the absorbing kernel has >= parallelism
// for the absorbed work.
// ---------------------------------------------------------------------------

typedef __attribute__((ext_vector_type(8))) short short8;
typedef __attribute__((ext_vector_type(4))) float floatx4;

#define AS1 __attribute__((address_space(1)))
#define AS3 __attribute__((address_space(3)))
#define GLD16(g, l) __builtin_amdgcn_global_load_lds((AS1 const unsigned int*)(g), (AS3 unsigned int*)(l), 16, 0, 0)

__device__ __forceinline__ float silu_f(float x) {
    return x / (1.0f + __expf(-x));
}

// RNE split of fp32 into two bf16 (hi + lo)
__device__ __forceinline__ void split2(float x, unsigned short& hi, unsigned short& lo) {
    unsigned u = __float_as_uint(x);
    unsigned r = u + 0x7FFFu + ((u >> 16) & 1u);
    unsigned short h = (unsigned short)(r >> 16);
    float hf = __uint_as_float((unsigned)h << 16);
    float rem = x - hf;
    unsigned u2 = __float_as_uint(rem);
    unsigned r2 = u2 + 0x7FFFu + ((u2 >> 16) & 1u);
    hi = h;
    lo = (unsigned short)(r2 >> 16);
}

// ---------------- transpose + split, 64x64 tiles + A-build tail ------------
// W[K][N] f32 -> Th[N][K], Tl[N][K] bf16 (k-contiguous). nt reads.
// Tail blocks: h_one (32x1024) -> block-diagonal A[128][2048] hi/lo,
// including all zero regions (mirror blocks + dead rows 32-63 / 96-127).
__global__ __launch_bounds__(256)
void transpose_split_all(const float* __restrict__ w10, const float* __restrict__ w11,
                         const float* __restrict__ w12, const float* __restrict__ h_one,
                         unsigned short* __restrict__ t10h, unsigned short* __restrict__ t10l,
                         unsigned short* __restrict__ t11h, unsigned short* __restrict__ t11l,
                         unsigned short* __restrict__ t12h, unsigned short* __restrict__ t12l,
                         unsigned short* __restrict__ Ah, unsigned short* __restrict__ Al) {
    const int t = threadIdx.x;
    int id = blockIdx.x;

    if (id >= 8192) {
        // A-build tail: 8 blocks x 4096 elements (h_one = 32x1024)
        const int tb = id - 8192;
        const int base = tb * 4096 + t * 16;
        const ushort4 zz = {0, 0, 0, 0};
        #pragma unroll
        for (int j = 0; j < 4; ++j) {
            const int f = base + 4 * j;
            const int r = f >> 10;
            const int c = f & 1023;
            floatx4 v = __builtin_nontemporal_load((const floatx4*)&h_one[f]);
            ushort4 hv, lv;
            split2(v.x, hv.x, lv.x);
            split2(v.y, hv.y, lv.y);
            split2(v.z, hv.z, lv.z);
            split2(v.w, hv.w, lv.w);
            const size_t o1 = (size_t)r * 2048 + c;                 // [H | 0] row r
            const size_t o2 = (size_t)(64 + r) * 2048 + 1024 + c;   // [0 | H] row 64+r
            *(ushort4*)&Ah[o1] = hv;
            *(ushort4*)&Al[o1] = lv;
            *(ushort4*)&Ah[o2] = hv;
            *(ushort4*)&Al[o2] = lv;
            // zero mirrors (rows 0-31 cols 1024+, rows 64-95 cols 0-1023)
            const size_t z1 = (size_t)r * 2048 + 1024 + c;
            const size_t z2 = (size_t)(64 + r) * 2048 + c;
            *(ushort4*)&Ah[z1] = zz;
            *(ushort4*)&Al[z1] = zz;
            *(ushort4*)&Ah[z2] = zz;
            *(ushort4*)&Al[z2] = zz;
        }
        // zero dead rows 32..63 and 96..127 (each block slices 1/8 of 64K els)
        const unsigned off1 = 32 * 2048, off2 = 96 * 2048;
        #pragma unroll
        for (int q = 0; q < 8; ++q) {
            const unsigned e = (unsigned)tb * 8192 + (unsigned)(q * 256 + t) * 4;
            *(ushort4*)&Ah[off1 + e] = zz;
            *(ushort4*)&Al[off1 + e] = zz;
            *(ushort4*)&Ah[off2 + e] = zz;
            *(ushort4*)&Al[off2 + e] = zz;
        }
        return;
    }

    const float* W;
    unsigned short *Th, *Tl;
    int K, N, nt, kt;
    if (id < 2048)       { W = w10; Th = t10h; Tl = t10l; K = 2048; N = 4096; nt = id & 63; kt = id >> 6; }
    else if (id < 6144)  { id -= 2048; W = w11; Th = t11h; Tl = t11l; K = 4096; N = 4096; nt = id & 63; kt = id >> 6; }
    else                 { id -= 6144; W = w12; Th = t12h; Tl = t12l; K = 4096; N = 2048; nt = id & 31; kt = id >> 5; }

    __shared__ float tile[64][65];
    const int n0 = nt * 64;
    const int k0 = kt * 64;

    const int lrow = t >> 4;        // 0..15
    const int lcol = (t & 15) * 4;  // 0..60
    #pragma unroll
    for (int p = 0; p < 4; ++p) {
        const int r = p * 16 + lrow;
        floatx4 v = __builtin_nontemporal_load((const floatx4*)&W[(size_t)(k0 + r) * N + n0 + lcol]);
        tile[r][lcol + 0] = v.x;
        tile[r][lcol + 1] = v.y;
        tile[r][lcol + 2] = v.z;
        tile[r][lcol + 3] = v.w;
    }
    __syncthreads();

    const int srow0 = t >> 3;       // 0..31
    const int koff  = (t & 7) * 8;  // 0..56
    #pragma unroll
    for (int p = 0; p < 2; ++p) {
        const int sn = p * 32 + srow0;
        unsigned short hv[8], lv[8];
        #pragma unroll
        for (int kk = 0; kk < 8; ++kk)
            split2(tile[koff + kk][sn], hv[kk], lv[kk]);
        unsigned short* dh = &Th[(size_t)(n0 + sn) * K + k0 + koff];
        unsigned short* dl = &Tl[(size_t)(n0 + sn) * K + k0 + koff];
        *(short8*)dh = *(short8*)&hv[0];
        *(short8*)dl = *(short8*)&lv[0];
    }
}

// ---------------- m97-style LDS-staged GEMM, 128x128 tile ------------------
__global__ __launch_bounds__(256, 2)
void gemm128(const unsigned short* __restrict__ Ah, const unsigned short* __restrict__ Al,
             const unsigned short* __restrict__ Bh, const unsigned short* __restrict__ Bl,
             int K, float* __restrict__ Cpart, int N, int Mtot, int kc)
{
    __shared__ __align__(16) unsigned short As[2][128][32];
    __shared__ __align__(16) unsigned short Bs[2][128][32];

    const int tid  = threadIdx.x;
    const int lane = tid & 63;
    const int wid  = tid >> 6;
    const int n0 = blockIdx.x * 128;
    const int m0 = blockIdx.y * 128;
    const int kbase = blockIdx.z * kc;

    const int srow   = wid * 32 + (lane >> 2);
    const int schunk = (lane & 3) ^ ((srow >> 1) & 3);
    const unsigned short* gA0h = Ah + (size_t)(m0 + srow) * K + kbase + schunk * 8;
    const unsigned short* gA1h = gA0h + (size_t)16 * K;
    const unsigned short* gA0l = Al + (size_t)(m0 + srow) * K + kbase + schunk * 8;
    const unsigned short* gA1l = gA0l + (size_t)16 * K;
    const unsigned short* gB0h = Bh + (size_t)(n0 + srow) * K + kbase + schunk * 8;
    const unsigned short* gB1h = gB0h + (size_t)16 * K;
    const unsigned short* gB0l = Bl + (size_t)(n0 + srow) * K + kbase + schunk * 8;
    const unsigned short* gB1l = gB0l + (size_t)16 * K;
    unsigned short* lA0h = &As[0][wid * 32][0];
    unsigned short* lA1h = &As[0][wid * 32 + 16][0];
    unsigned short* lA0l = &As[1][wid * 32][0];
    unsigned short* lA1l = &As[1][wid * 32 + 16][0];
    unsigned short* lB0h = &Bs[0][wid * 32][0];
    unsigned short* lB1h = &Bs[0][wid * 32 + 16][0];
    unsigned short* lB0l = &Bs[1][wid * 32][0];
    unsigned short* lB1l = &Bs[1][wid * 32 + 16][0];

    const int mhalf = wid >> 1;
    const int nhalf = wid & 1;
    const int lm = lane & 15;
    const int q  = lane >> 4;
    int aoffs[4], boffs[4];
    #pragma unroll
    for (int f = 0; f < 4; ++f) {
        int arow = mhalf * 64 + f * 16 + lm;
        int aslot = q ^ ((arow >> 1) & 3);
        aoffs[f] = arow * 32 + aslot * 8;
        int brow = nhalf * 64 + f * 16 + lm;
        int bslot = q ^ ((brow >> 1) & 3);
        boffs[f] = brow * 32 + bslot * 8;
    }
    const unsigned short* AsF = &As[0][0][0];
    const unsigned short* BsF = &Bs[0][0][0];

    floatx4 acc[4][4];
    #pragma unroll
    for (int ms = 0; ms < 4; ++ms)
        #pragma unroll
        for (int ns = 0; ns < 4; ++ns)
            acc[ms][ns] = (floatx4){0.f, 0.f, 0.f, 0.f};

    const int S = kc >> 5;
    for (int s = 0; s < S; ++s) {
        const int ko = s << 5;
        __syncthreads();
        GLD16(gA0h + ko, lA0h);
        GLD16(gA1h + ko, lA1h);
        GLD16(gA0l + ko, lA0l);
        GLD16(gA1l + ko, lA1l);
        GLD16(gB0h + ko, lB0h);
        GLD16(gB1h + ko, lB1h);
        GLD16(gB0l + ko, lB0l);
        GLD16(gB1l + ko, lB1l);
        __syncthreads();

        short8 afh[4], afl[4], bfh[4], bfl[4];
        #pragma unroll
        for (int f = 0; f < 4; ++f) {
            afh[f] = *(const short8*)(AsF + aoffs[f]);
            afl[f] = *(const short8*)(AsF + 4096 + aoffs[f]);
            bfh[f] = *(const short8*)(BsF + boffs[f]);
            bfl[f] = *(const short8*)(BsF + 4096 + boffs[f]);
        }
        #pragma unroll
        for (int ms = 0; ms < 4; ++ms)
            #pragma unroll
            for (int ns = 0; ns < 4; ++ns)
                acc[ms][ns] = __builtin_amdgcn_mfma_f32_16x16x32_bf16(afh[ms], bfh[ns], acc[ms][ns], 0, 0, 0);
        #pragma unroll
        for (int ms = 0; ms < 4; ++ms)
            #pragma unroll
            for (int ns = 0; ns < 4; ++ns)
                acc[ms][ns] = __builtin_amdgcn_mfma_f32_16x16x32_bf16(afl[ms], bfh[ns], acc[ms][ns], 0, 0, 0);
        #pragma unroll
        for (int ms = 0; ms < 4; ++ms)
            #pragma unroll
            for (int ns = 0; ns < 4; ++ns)
                acc[ms][ns] = __builtin_amdgcn_mfma_f32_16x16x32_bf16(afh[ms], bfl[ns], acc[ms][ns], 0, 0, 0);
    }

    float* Cp = Cpart + (size_t)blockIdx.z * Mtot * N;
    const int lr = (lane >> 4) * 4;
    #pragma unroll
    for (int ms = 0; ms < 4; ++ms)
        #pragma unroll
        for (int ns = 0; ns < 4; ++ns)
            #pragma unroll
            for (int r = 0; r < 4; ++r)
                Cp[(size_t)(m0 + mhalf * 64 + ms * 16 + lr + r) * N + n0 + nhalf * 64 + ns * 16 + lm] = acc[ms][ns][r];
}

// ---------------- small kernels ----------------
// PQ = PartPQ[z][128][4096]: rows 0..63 P-chunks, rows 64..127 Q-chunks.
// grid (480, 4): x = pair row, y = column quarter.
__global__ __launch_bounds__(256)
void build_y1_kernel(const float* __restrict__ PQ, const float* __restrict__ b1,
                     unsigned short* __restrict__ Y1h, unsigned short* __restrict__ Y1l) {
    const int r = blockIdx.x;
    const int g = r / 240;
    const int rem = r % 240;
    const int o = rem / 120;
    const int p = rem % 120;
    int i = 0, pp = p, cnt = 15;
    while (pp >= cnt) { pp -= cnt; cnt--; i++; }
    const int j = i + 1 + pp;
    const int ai = g * 16 + (o ? j : i);
    const int bi = g * 16 + (o ? i : j);
    const size_t chunk4 = (size_t)128 * 4096 / 4;
    const float4* Pr0 = (const float4*)(PQ + (size_t)ai * 4096);
    const float4* Qr0 = (const float4*)(PQ + (size_t)(64 + bi) * 4096);
    const float4* Br  = (const float4*)b1;
    const int c = blockIdx.y * 256 + threadIdx.x;   // 0..1023 (float4 units)
    float4 bv = Br[c];
    float s0 = bv.x, s1 = bv.y, s2 = bv.z, s3 = bv.w;
    #pragma unroll
    for (int cc = 0; cc < 4; ++cc) {
        float4 pv = Pr0[c + cc * chunk4];
        float4 qv = Qr0[c + cc * chunk4];
        s0 += pv.x + qv.x;
        s1 += pv.y + qv.y;
        s2 += pv.z + qv.z;
        s3 += pv.w + qv.w;
    }
    s0 = silu_f(s0);
    s1 = silu_f(s1);
    s2 = silu_f(s2);
    s3 = silu_f(s3);
    ushort4 hv, lv;
    split2(s0, hv.x, lv.x);
    split2(s1, hv.y, lv.y);
    split2(s2, hv.z, lv.z);
    split2(s3, hv.w, lv.w);
    *(ushort4*)&Y1h[(size_t)r * 4096 + c * 4] = hv;
    *(ushort4*)&Y1l[(size_t)r * 4096 + c * 4] = lv;
}

__global__ __launch_bounds__(256)
void reduce4_silu_split(const float* __restrict__ Part, const float* __restrict__ bias,
                        unsigned short* __restrict__ Yh, unsigned short* __restrict__ Yl) {
    const size_t idx = (size_t)blockIdx.x * 256 + threadIdx.x;
    const size_t stride4 = (size_t)512 * 4096 / 4;
    const float4* p = (const float4*)Part;
    float4 v0 = p[idx], v1 = p[idx + stride4], v2 = p[idx + 2 * stride4], v3 = p[idx + 3 * stride4];
    const int col = (int)((idx * 4) & 4095);
    float4 b = *(const float4*)&bias[col];
    float s0 = silu_f(v0.x + v1.x + v2.x + v3.x + b.x);
    float s1 = silu_f(v0.y + v1.y + v2.y + v3.y + b.y);
    float s2 = silu_f(v0.z + v1.z + v2.z + v3.z + b.z);
    float s3 = silu_f(v0.w + v1.w + v2.w + v3.w + b.w);
    ushort4 hv, lv;
    split2(s0, hv.x, lv.x);
    split2(s1, hv.y, lv.y);
    split2(s2, hv.z, lv.z);
    split2(s3, hv.w, lv.w);
    *(ushort4*)&Yh[idx * 4] = hv;
    *(ushort4*)&Yl[idx * 4] = lv;
}

__global__ __launch_bounds__(256)
void reduce8_bias(const float* __restrict__ Part, const float* __restrict__ bias,
                  float* __restrict__ Hb) {
    const size_t idx = (size_t)blockIdx.x * 256 + threadIdx.x;
    const size_t stride4 = (size_t)512 * 2048 / 4;
    const float4* p = (const float4*)Part;
    float4 s = p[idx];
    #pragma unroll
    for (int c = 1; c < 8; ++c) {
        float4 v = p[idx + c * stride4];
        s.x += v.x; s.y += v.y; s.z += v.z; s.w += v.w;
    }
    const int col = (int)((idx * 4) & 2047);
    float4 b = *(const float4*)&bias[col];
    s.x += b.x; s.y += b.y; s.z += b.z; s.w += b.w;
    *(float4*)&Hb[idx * 4] = s;
}

// grid (8,2,4): partial products of 30 pairs each -> a_part[(g*4+cz)][2048]
__global__ __launch_bounds__(256)
void reduce_prod_kernel(const float* __restrict__ H, float* __restrict__ a_part) {
    const int g = blockIdx.y;
    const int cz = blockIdx.z;
    const int c = blockIdx.x * 256 + threadIdx.x;
    const float* base = H + (size_t)g * 240 * 2048 + c;
    float prod = 1.0f;
    const int p0 = cz * 30;
    for (int p = p0; p < p0 + 30; ++p) {
        float f = base[(size_t)p * 2048] - base[(size_t)(120 + p) * 2048];
        prod *= f;
    }
    a_part[(size_t)((g << 2) | cz) * 2048 + c] = prod;
}

// Part2[kc][g][n] = sum_{k in chunk kc} a[g][k] * W2_0[k][n]
// a[g][k] = prod of 4 partials. grid (8 nc, 16 kc).
__global__ __launch_bounds__(256)
void mlp2_acc2_kernel(const float* __restrict__ a_part, const float* __restrict__ W,
                      float* __restrict__ Part2) {
    __shared__ float a0s[128], a1s[128];
    const int kc = blockIdx.y, nc = blockIdx.x, t = threadIdx.x;
    if (t < 128) {
        const int k = kc * 128 + t;
        a0s[t] = a_part[k] * a_part[2048 + k] * a_part[4096 + k] * a_part[6144 + k];
        a1s[t] = a_part[8192 + k] * a_part[10240 + k] * a_part[12288 + k] * a_part[14336 + k];
    }
    __syncthreads();
    const int n = nc * 256 + t;
    const float* Wp = W + (size_t)(kc * 128) * 2048 + n;
    float s0 = 0.f, s1 = 0.f;
    #pragma unroll 8
    for (int kk = 0; kk < 128; ++kk) {
        float w = Wp[(size_t)kk * 2048];
        s0 = fmaf(a0s[kk], w, s0);
        s1 = fmaf(a1s[kk], w, s1);
    }
    Part2[kc * 4096 + n] = s0;
    Part2[kc * 4096 + 2048 + n] = s1;
}

__global__ __launch_bounds__(256)
void finalize_kernel(const float* __restrict__ Part2, const float* __restrict__ b2_0,
                     const float* __restrict__ w2_1, const float* __restrict__ b2_1,
                     float* __restrict__ out) {
    __shared__ float red[256];
    const int tid = threadIdx.x;
    float result = 0.0f;
    for (int g = 0; g < 2; ++g) {
        float s = 0.f;
        for (int n = tid; n < 2048; n += 256) {
            float acc = b2_0[n];
            #pragma unroll
            for (int kc = 0; kc < 16; ++kc)
                acc += Part2[kc * 4096 + g * 2048 + n];
            s += tanhf(acc) * w2_1[n];
        }
        red[tid] = s;
        __syncthreads();
        for (int off = 128; off > 0; off >>= 1) {
            if (tid < off) red[tid] += red[tid + off];
            __syncthreads();
        }
        if (tid == 0) result += logf(fabsf(red[0] + b2_1[0]));
        __syncthreads();
    }
    if (tid == 0) out[0] = result;
}

extern "C" void kernel_launch(void* const* d_in, const int* in_sizes, int n_in,
                              void* d_out, int out_size, void* d_ws, size_t ws_size,
                              hipStream_t stream) {
    const float* h_one = (const float*)d_in[0];
    const float* w1_0  = (const float*)d_in[1];
    const float* b1_0  = (const float*)d_in[2];
    const float* w1_1  = (const float*)d_in[3];
    const float* b1_1  = (const float*)d_in[4];
    const float* w1_2  = (const float*)d_in[5];
    const float* b1_2  = (const float*)d_in[6];
    const float* w2_0  = (const float*)d_in[7];
    const float* b2_0  = (const float*)d_in[8];
    const float* w2_1  = (const float*)d_in[9];
    const float* b2_1  = (const float*)d_in[10];
    float* out = (float*)d_out;

    char* ws = (char*)d_ws;
    // region0: W10t (33.5 MB), later PartL1 (4 x 512 x 4096 f32)
    unsigned short* W10t_h = (unsigned short*)ws;
    unsigned short* W10t_l = W10t_h + (size_t)4096 * 2048;
    float*          PartL1 = (float*)ws;
    ws += (size_t)4096 * 2048 * 2 * 2;
    // region1: W11t (67 MB), later PartL2 (8 x 512 x 2048 f32)
    unsigned short* W11t_h = (unsigned short*)ws;
    unsigned short* W11t_l = W11t_h + (size_t)4096 * 4096;
    float*          PartL2 = (float*)ws;
    ws += (size_t)4096 * 4096 * 2 * 2;
    // region2: W12t (33.5 MB), live through L2
    unsigned short* W12t_h = (unsigned short*)ws;
    unsigned short* W12t_l = W12t_h + (size_t)2048 * 4096;
    ws += (size_t)2048 * 4096 * 2 * 2;
    // block-diagonal A for PQ gemm: [128][2048] hi + lo (1 MB)
    unsigned short* Ah  = (unsigned short*)ws;  ws += (size_t)128 * 2048 * 2;
    unsigned short* Al  = (unsigned short*)ws;  ws += (size_t)128 * 2048 * 2;
    float* PQ  = (float*)ws;                    ws += (size_t)4 * 128 * 4096 * 4;
    unsigned short* Y1h = (unsigned short*)ws;  ws += (size_t)512 * 4096 * 2;
    unsigned short* Y1l = (unsigned short*)ws;  ws += (size_t)512 * 4096 * 2;
    unsigned short* Y2h = (unsigned short*)ws;  ws += (size_t)512 * 4096 * 2;
    unsigned short* Y2l = (unsigned short*)ws;  ws += (size_t)512 * 4096 * 2;
    float* Hb    = (float*)ws;                  ws += (size_t)512 * 2048 * 4;
    float* a_part = (float*)ws;                 ws += (size_t)8 * 2048 * 4;
    float* Part2 = (float*)ws;                  ws += (size_t)16 * 2 * 2048 * 4;

    // weight transposes + A-build (incl. zeroing) — no memset needed
    transpose_split_all<<<8200, 256, 0, stream>>>(w1_0, w1_1, w1_2, h_one,
                                                  W10t_h, W10t_l, W11t_h, W11t_l,
                                                  W12t_h, W12t_l, Ah, Al);

    // PQ: one gemm128, M=128 (P rows 0..63, Q rows 64..127), N=4096, K=2048, Z=4
    gemm128<<<dim3(32, 1, 4), 256, 0, stream>>>(Ah, Al, W10t_h, W10t_l, 2048,
                                                PQ, 4096, 128, 512);
    build_y1_kernel<<<dim3(480, 4), 256, 0, stream>>>(PQ, b1_0, Y1h, Y1l);

    // L1: Y2 = silu(Y1 @ W1_1 + b1_1)  M=512 N=4096 K=4096, Z=4
    gemm128<<<dim3(32, 4, 4), 256, 0, stream>>>(Y1h, Y1l, W11t_h, W11t_l, 4096,
                                                PartL1, 4096, 512, 1024);
    reduce4_silu_split<<<2048, 256, 0, stream>>>(PartL1, b1_1, Y2h, Y2l);

    // L2: Hb = Y2 @ W1_2 + b1_2  M=512 N=2048 K=4096, Z=8
    gemm128<<<dim3(16, 4, 8), 256, 0, stream>>>(Y2h, Y2l, W12t_h, W12t_l, 4096,
                                                PartL2, 2048, 512, 512);
    reduce8_bias<<<1024, 256, 0, stream>>>(PartL2, b1_2, Hb);

    // tail (4 separate launches — measured cheaper than any cross-block sync)
    reduce_prod_kernel<<<dim3(8, 2, 4), 256, 0, stream>>>(Hb, a_part);
    mlp2_acc2_kernel<<<dim3(8, 16), 256, 0, stream>>>(a_part, w2_0, Part2);
    finalize_kernel<<<1, 256, 0, stream>>>(Part2, b2_0, w2_1, b2_1, out);
}

// Round 12
// 319.995 us; speedup vs baseline: 1.1647x; 1.0410x over previous
//
#include <hip/hip_runtime.h>
#include <hip/hip_bf16.h>
#include <math.h>

// ---------------------------------------------------------------------------
// Round 17: BK=64 gemm128 via two verified BK=32 panels (barrier amortization).
//   - r15/r16 proved the ~155us non-kernel time is FIXED harness overhead
//     (launch-count changes have zero effect). Addressable time = ~178us of
//     kernels, led by the gemms at the m97 2-barrier structure ceiling.
//   - The structure's known ~20% stall is the vmcnt/lgkm drain per K-step
//     barrier. This round halves barrier count: K-step 32 -> 64, staged as
//     TWO 32-wide panels each keeping the exact existing layout + XOR swizzle
//     (zero new bank-conflict derivation; accumulation order bit-identical:
//     panel0 = old even step, panel1 = old odd step).
//   - LDS 32->64KB/block: still 2 blocks/CU (already the occupancy), VGPR
//     headroom 256/wave at 2 waves/SIMD so panel-1 frags get own registers.
//   - Everything else identical to r16 (333.1us measured).
// ---------------------------------------------------------------------------

typedef __attribute__((ext_vector_type(8))) short short8;
typedef __attribute__((ext_vector_type(4))) float floatx4;

#define AS1 __attribute__((address_space(1)))
#define AS3 __attribute__((address_space(3)))
#define GLD16(g, l) __builtin_amdgcn_global_load_lds((AS1 const unsigned int*)(g), (AS3 unsigned int*)(l), 16, 0, 0)

__device__ __forceinline__ float silu_f(float x) {
    return x / (1.0f + __expf(-x));
}

// RNE split of fp32 into two bf16 (hi + lo)
__device__ __forceinline__ void split2(float x, unsigned short& hi, unsigned short& lo) {
    unsigned u = __float_as_uint(x);
    unsigned r = u + 0x7FFFu + ((u >> 16) & 1u);
    unsigned short h = (unsigned short)(r >> 16);
    float hf = __uint_as_float((unsigned)h << 16);
    float rem = x - hf;
    unsigned u2 = __float_as_uint(rem);
    unsigned r2 = u2 + 0x7FFFu + ((u2 >> 16) & 1u);
    hi = h;
    lo = (unsigned short)(r2 >> 16);
}

// ---------------- transpose + split, 64x64 tiles + A-build tail ------------
// W[K][N] f32 -> Th[N][K], Tl[N][K] bf16 (k-contiguous). nt reads.
// Tail blocks: h_one (32x1024) -> block-diagonal A[128][2048] hi/lo,
// including all zero regions (mirror blocks + dead rows 32-63 / 96-127).
__global__ __launch_bounds__(256)
void transpose_split_all(const float* __restrict__ w10, const float* __restrict__ w11,
                         const float* __restrict__ w12, const float* __restrict__ h_one,
                         unsigned short* __restrict__ t10h, unsigned short* __restrict__ t10l,
                         unsigned short* __restrict__ t11h, unsigned short* __restrict__ t11l,
                         unsigned short* __restrict__ t12h, unsigned short* __restrict__ t12l,
                         unsigned short* __restrict__ Ah, unsigned short* __restrict__ Al) {
    const int t = threadIdx.x;
    int id = blockIdx.x;

    if (id >= 8192) {
        // A-build tail: 8 blocks x 4096 elements (h_one = 32x1024)
        const int tb = id - 8192;
        const int base = tb * 4096 + t * 16;
        const ushort4 zz = {0, 0, 0, 0};
        #pragma unroll
        for (int j = 0; j < 4; ++j) {
            const int f = base + 4 * j;
            const int r = f >> 10;
            const int c = f & 1023;
            floatx4 v = __builtin_nontemporal_load((const floatx4*)&h_one[f]);
            ushort4 hv, lv;
            split2(v.x, hv.x, lv.x);
            split2(v.y, hv.y, lv.y);
            split2(v.z, hv.z, lv.z);
            split2(v.w, hv.w, lv.w);
            const size_t o1 = (size_t)r * 2048 + c;                 // [H | 0] row r
            const size_t o2 = (size_t)(64 + r) * 2048 + 1024 + c;   // [0 | H] row 64+r
            *(ushort4*)&Ah[o1] = hv;
            *(ushort4*)&Al[o1] = lv;
            *(ushort4*)&Ah[o2] = hv;
            *(ushort4*)&Al[o2] = lv;
            // zero mirrors (rows 0-31 cols 1024+, rows 64-95 cols 0-1023)
            const size_t z1 = (size_t)r * 2048 + 1024 + c;
            const size_t z2 = (size_t)(64 + r) * 2048 + c;
            *(ushort4*)&Ah[z1] = zz;
            *(ushort4*)&Al[z1] = zz;
            *(ushort4*)&Ah[z2] = zz;
            *(ushort4*)&Al[z2] = zz;
        }
        // zero dead rows 32..63 and 96..127 (each block slices 1/8 of 64K els)
        const unsigned off1 = 32 * 2048, off2 = 96 * 2048;
        #pragma unroll
        for (int q = 0; q < 8; ++q) {
            const unsigned e = (unsigned)tb * 8192 + (unsigned)(q * 256 + t) * 4;
            *(ushort4*)&Ah[off1 + e] = zz;
            *(ushort4*)&Al[off1 + e] = zz;
            *(ushort4*)&Ah[off2 + e] = zz;
            *(ushort4*)&Al[off2 + e] = zz;
        }
        return;
    }

    const float* W;
    unsigned short *Th, *Tl;
    int K, N, nt, kt;
    if (id < 2048)       { W = w10; Th = t10h; Tl = t10l; K = 2048; N = 4096; nt = id & 63; kt = id >> 6; }
    else if (id < 6144)  { id -= 2048; W = w11; Th = t11h; Tl = t11l; K = 4096; N = 4096; nt = id & 63; kt = id >> 6; }
    else                 { id -= 6144; W = w12; Th = t12h; Tl = t12l; K = 4096; N = 2048; nt = id & 31; kt = id >> 5; }

    __shared__ float tile[64][65];
    const int n0 = nt * 64;
    const int k0 = kt * 64;

    const int lrow = t >> 4;        // 0..15
    const int lcol = (t & 15) * 4;  // 0..60
    #pragma unroll
    for (int p = 0; p < 4; ++p) {
        const int r = p * 16 + lrow;
        floatx4 v = __builtin_nontemporal_load((const floatx4*)&W[(size_t)(k0 + r) * N + n0 + lcol]);
        tile[r][lcol + 0] = v.x;
        tile[r][lcol + 1] = v.y;
        tile[r][lcol + 2] = v.z;
        tile[r][lcol + 3] = v.w;
    }
    __syncthreads();

    const int srow0 = t >> 3;       // 0..31
    const int koff  = (t & 7) * 8;  // 0..56
    #pragma unroll
    for (int p = 0; p < 2; ++p) {
        const int sn = p * 32 + srow0;
        unsigned short hv[8], lv[8];
        #pragma unroll
        for (int kk = 0; kk < 8; ++kk)
            split2(tile[koff + kk][sn], hv[kk], lv[kk]);
        unsigned short* dh = &Th[(size_t)(n0 + sn) * K + k0 + koff];
        unsigned short* dl = &Tl[(size_t)(n0 + sn) * K + k0 + koff];
        *(short8*)dh = *(short8*)&hv[0];
        *(short8*)dl = *(short8*)&lv[0];
    }
}

// ---------------- LDS-staged GEMM, 128x128 tile, BK=64 (2 panels) ----------
// Panels keep the verified BK=32 layout + XOR swizzle; barriers halved.
// LDS shorts layout: [hi-p0 | hi-p1 | lo-p0 | lo-p1] x 4096 each, A then B.
__global__ __launch_bounds__(256, 2)
void gemm128(const unsigned short* __restrict__ Ah, const unsigned short* __restrict__ Al,
             const unsigned short* __restrict__ Bh, const unsigned short* __restrict__ Bl,
             int K, float* __restrict__ Cpart, int N, int Mtot, int kc)
{
    __shared__ __align__(16) unsigned short As[4][128][32];
    __shared__ __align__(16) unsigned short Bs[4][128][32];

    const int tid  = threadIdx.x;
    const int lane = tid & 63;
    const int wid  = tid >> 6;
    const int n0 = blockIdx.x * 128;
    const int m0 = blockIdx.y * 128;
    const int kbase = blockIdx.z * kc;

    const int srow   = wid * 32 + (lane >> 2);
    const int schunk = (lane & 3) ^ ((srow >> 1) & 3);
    const unsigned short* gA0h = Ah + (size_t)(m0 + srow) * K + kbase + schunk * 8;
    const unsigned short* gA1h = gA0h + (size_t)16 * K;
    const unsigned short* gA0l = Al + (size_t)(m0 + srow) * K + kbase + schunk * 8;
    const unsigned short* gA1l = gA0l + (size_t)16 * K;
    const unsigned short* gB0h = Bh + (size_t)(n0 + srow) * K + kbase + schunk * 8;
    const unsigned short* gB1h = gB0h + (size_t)16 * K;
    const unsigned short* gB0l = Bl + (size_t)(n0 + srow) * K + kbase + schunk * 8;
    const unsigned short* gB1l = gB0l + (size_t)16 * K;

    // wave-uniform LDS staging bases (each GLD16 covers 16 rows x 32 shorts)
    unsigned short* sA = &As[0][wid * 32][0];
    unsigned short* sB = &Bs[0][wid * 32][0];

    const int mhalf = wid >> 1;
    const int nhalf = wid & 1;
    const int lm = lane & 15;
    const int q  = lane >> 4;
    int aoffs[4], boffs[4];
    #pragma unroll
    for (int f = 0; f < 4; ++f) {
        int arow = mhalf * 64 + f * 16 + lm;
        int aslot = q ^ ((arow >> 1) & 3);
        aoffs[f] = arow * 32 + aslot * 8;
        int brow = nhalf * 64 + f * 16 + lm;
        int bslot = q ^ ((brow >> 1) & 3);
        boffs[f] = brow * 32 + bslot * 8;
    }
    const unsigned short* AsF = &As[0][0][0];
    const unsigned short* BsF = &Bs[0][0][0];

    floatx4 acc[4][4];
    #pragma unroll
    for (int ms = 0; ms < 4; ++ms)
        #pragma unroll
        for (int ns = 0; ns < 4; ++ns)
            acc[ms][ns] = (floatx4){0.f, 0.f, 0.f, 0.f};

    const int S = kc >> 6;
    for (int s = 0; s < S; ++s) {
        const int ko = s << 6;
        __syncthreads();
        // panel 0 (k offset +0) and panel 1 (+32), hi then lo, A then B
        GLD16(gA0h + ko,      sA + 0);
        GLD16(gA1h + ko,      sA + 512);
        GLD16(gA0h + ko + 32, sA + 4096);
        GLD16(gA1h + ko + 32, sA + 4608);
        GLD16(gA0l + ko,      sA + 8192);
        GLD16(gA1l + ko,      sA + 8704);
        GLD16(gA0l + ko + 32, sA + 12288);
        GLD16(gA1l + ko + 32, sA + 12800);
        GLD16(gB0h + ko,      sB + 0);
        GLD16(gB1h + ko,      sB + 512);
        GLD16(gB0h + ko + 32, sB + 4096);
        GLD16(gB1h + ko + 32, sB + 4608);
        GLD16(gB0l + ko,      sB + 8192);
        GLD16(gB1l + ko,      sB + 8704);
        GLD16(gB0l + ko + 32, sB + 12288);
        GLD16(gB1l + ko + 32, sB + 12800);
        __syncthreads();

        short8 afh0[4], afl0[4], bfh0[4], bfl0[4];
        short8 afh1[4], afl1[4], bfh1[4], bfl1[4];
        #pragma unroll
        for (int f = 0; f < 4; ++f) {
            afh0[f] = *(const short8*)(AsF + aoffs[f]);
            afl0[f] = *(const short8*)(AsF + 8192 + aoffs[f]);
            afh1[f] = *(const short8*)(AsF + 4096 + aoffs[f]);
            afl1[f] = *(const short8*)(AsF + 12288 + aoffs[f]);
            bfh0[f] = *(const short8*)(BsF + boffs[f]);
            bfl0[f] = *(const short8*)(BsF + 8192 + boffs[f]);
            bfh1[f] = *(const short8*)(BsF + 4096 + boffs[f]);
            bfl1[f] = *(const short8*)(BsF + 12288 + boffs[f]);
        }
        // panel 0 (= old even K-step): hh, lh, hl
        #pragma unroll
        for (int ms = 0; ms < 4; ++ms)
            #pragma unroll
            for (int ns = 0; ns < 4; ++ns)
                acc[ms][ns] = __builtin_amdgcn_mfma_f32_16x16x32_bf16(afh0[ms], bfh0[ns], acc[ms][ns], 0, 0, 0);
        #pragma unroll
        for (int ms = 0; ms < 4; ++ms)
            #pragma unroll
            for (int ns = 0; ns < 4; ++ns)
                acc[ms][ns] = __builtin_amdgcn_mfma_f32_16x16x32_bf16(afl0[ms], bfh0[ns], acc[ms][ns], 0, 0, 0);
        #pragma unroll
        for (int ms = 0; ms < 4; ++ms)
            #pragma unroll
            for (int ns = 0; ns < 4; ++ns)
                acc[ms][ns] = __builtin_amdgcn_mfma_f32_16x16x32_bf16(afh0[ms], bfl0[ns], acc[ms][ns], 0, 0, 0);
        // panel 1 (= old odd K-step): hh, lh, hl
        #pragma unroll
        for (int ms = 0; ms < 4; ++ms)
            #pragma unroll
            for (int ns = 0; ns < 4; ++ns)
                acc[ms][ns] = __builtin_amdgcn_mfma_f32_16x16x32_bf16(afh1[ms], bfh1[ns], acc[ms][ns], 0, 0, 0);
        #pragma unroll
        for (int ms = 0; ms < 4; ++ms)
            #pragma unroll
            for (int ns = 0; ns < 4; ++ns)
                acc[ms][ns] = __builtin_amdgcn_mfma_f32_16x16x32_bf16(afl1[ms], bfh1[ns], acc[ms][ns], 0, 0, 0);
        #pragma unroll
        for (int ms = 0; ms < 4; ++ms)
            #pragma unroll
            for (int ns = 0; ns < 4; ++ns)
                acc[ms][ns] = __builtin_amdgcn_mfma_f32_16x16x32_bf16(afh1[ms], bfl1[ns], acc[ms][ns], 0, 0, 0);
    }

    float* Cp = Cpart + (size_t)blockIdx.z * Mtot * N;
    const int lr = (lane >> 4) * 4;
    #pragma unroll
    for (int ms = 0; ms < 4; ++ms)
        #pragma unroll
        for (int ns = 0; ns < 4; ++ns)
            #pragma unroll
            for (int r = 0; r < 4; ++r)
                Cp[(size_t)(m0 + mhalf * 64 + ms * 16 + lr + r) * N + n0 + nhalf * 64 + ns * 16 + lm] = acc[ms][ns][r];
}

// ---------------- small kernels ----------------
// PQ = PartPQ[z][128][4096]: rows 0..63 P-chunks, rows 64..127 Q-chunks.
// grid (480, 4): x = pair row, y = column quarter.
__global__ __launch_bounds__(256)
void build_y1_kernel(const float* __restrict__ PQ, const float* __restrict__ b1,
                     unsigned short* __restrict__ Y1h, unsigned short* __restrict__ Y1l) {
    const int r = blockIdx.x;
    const int g = r / 240;
    const int rem = r % 240;
    const int o = rem / 120;
    const int p = rem % 120;
    int i = 0, pp = p, cnt = 15;
    while (pp >= cnt) { pp -= cnt; cnt--; i++; }
    const int j = i + 1 + pp;
    const int ai = g * 16 + (o ? j : i);
    const int bi = g * 16 + (o ? i : j);
    const size_t chunk4 = (size_t)128 * 4096 / 4;
    const float4* Pr0 = (const float4*)(PQ + (size_t)ai * 4096);
    const float4* Qr0 = (const float4*)(PQ + (size_t)(64 + bi) * 4096);
    const float4* Br  = (const float4*)b1;
    const int c = blockIdx.y * 256 + threadIdx.x;   // 0..1023 (float4 units)
    float4 bv = Br[c];
    float s0 = bv.x, s1 = bv.y, s2 = bv.z, s3 = bv.w;
    #pragma unroll
    for (int cc = 0; cc < 4; ++cc) {
        float4 pv = Pr0[c + cc * chunk4];
        float4 qv = Qr0[c + cc * chunk4];
        s0 += pv.x + qv.x;
        s1 += pv.y + qv.y;
        s2 += pv.z + qv.z;
        s3 += pv.w + qv.w;
    }
    s0 = silu_f(s0);
    s1 = silu_f(s1);
    s2 = silu_f(s2);
    s3 = silu_f(s3);
    ushort4 hv, lv;
    split2(s0, hv.x, lv.x);
    split2(s1, hv.y, lv.y);
    split2(s2, hv.z, lv.z);
    split2(s3, hv.w, lv.w);
    *(ushort4*)&Y1h[(size_t)r * 4096 + c * 4] = hv;
    *(ushort4*)&Y1l[(size_t)r * 4096 + c * 4] = lv;
}

__global__ __launch_bounds__(256)
void reduce4_silu_split(const float* __restrict__ Part, const float* __restrict__ bias,
                        unsigned short* __restrict__ Yh, unsigned short* __restrict__ Yl) {
    const size_t idx = (size_t)blockIdx.x * 256 + threadIdx.x;
    const size_t stride4 = (size_t)512 * 4096 / 4;
    const float4* p = (const float4*)Part;
    float4 v0 = p[idx], v1 = p[idx + stride4], v2 = p[idx + 2 * stride4], v3 = p[idx + 3 * stride4];
    const int col = (int)((idx * 4) & 4095);
    float4 b = *(const float4*)&bias[col];
    float s0 = silu_f(v0.x + v1.x + v2.x + v3.x + b.x);
    float s1 = silu_f(v0.y + v1.y + v2.y + v3.y + b.y);
    float s2 = silu_f(v0.z + v1.z + v2.z + v3.z + b.z);
    float s3 = silu_f(v0.w + v1.w + v2.w + v3.w + b.w);
    ushort4 hv, lv;
    split2(s0, hv.x, lv.x);
    split2(s1, hv.y, lv.y);
    split2(s2, hv.z, lv.z);
    split2(s3, hv.w, lv.w);
    *(ushort4*)&Yh[idx * 4] = hv;
    *(ushort4*)&Yl[idx * 4] = lv;
}

__global__ __launch_bounds__(256)
void reduce8_bias(const float* __restrict__ Part, const float* __restrict__ bias,
                  float* __restrict__ Hb) {
    const size_t idx = (size_t)blockIdx.x * 256 + threadIdx.x;
    const size_t stride4 = (size_t)512 * 2048 / 4;
    const float4* p = (const float4*)Part;
    float4 s = p[idx];
    #pragma unroll
    for (int c = 1; c < 8; ++c) {
        float4 v = p[idx + c * stride4];
        s.x += v.x; s.y += v.y; s.z += v.z; s.w += v.w;
    }
    const int col = (int)((idx * 4) & 2047);
    float4 b = *(const float4*)&bias[col];
    s.x += b.x; s.y += b.y; s.z += b.z; s.w += b.w;
    *(float4*)&Hb[idx * 4] = s;
}

// grid (8,2,4): partial products of 30 pairs each -> a_part[(g*4+cz)][2048]
__global__ __launch_bounds__(256)
void reduce_prod_kernel(const float* __restrict__ H, float* __restrict__ a_part) {
    const int g = blockIdx.y;
    const int cz = blockIdx.z;
    const int c = blockIdx.x * 256 + threadIdx.x;
    const float* base = H + (size_t)g * 240 * 2048 + c;
    float prod = 1.0f;
    const int p0 = cz * 30;
    for (int p = p0; p < p0 + 30; ++p) {
        float f = base[(size_t)p * 2048] - base[(size_t)(120 + p) * 2048];
        prod *= f;
    }
    a_part[(size_t)((g << 2) | cz) * 2048 + c] = prod;
}

// Part2[kc][g][n] = sum_{k in chunk kc} a[g][k] * W2_0[k][n]
// a[g][k] = prod of 4 partials. grid (8 nc, 16 kc).
__global__ __launch_bounds__(256)
void mlp2_acc2_kernel(const float* __restrict__ a_part, const float* __restrict__ W,
                      float* __restrict__ Part2) {
    __shared__ float a0s[128], a1s[128];
    const int kc = blockIdx.y, nc = blockIdx.x, t = threadIdx.x;
    if (t < 128) {
        const int k = kc * 128 + t;
        a0s[t] = a_part[k] * a_part[2048 + k] * a_part[4096 + k] * a_part[6144 + k];
        a1s[t] = a_part[8192 + k] * a_part[10240 + k] * a_part[12288 + k] * a_part[14336 + k];
    }
    __syncthreads();
    const int n = nc * 256 + t;
    const float* Wp = W + (size_t)(kc * 128) * 2048 + n;
    float s0 = 0.f, s1 = 0.f;
    #pragma unroll 8
    for (int kk = 0; kk < 128; ++kk) {
        float w = Wp[(size_t)kk * 2048];
        s0 = fmaf(a0s[kk], w, s0);
        s1 = fmaf(a1s[kk], w, s1);
    }
    Part2[kc * 4096 + n] = s0;
    Part2[kc * 4096 + 2048 + n] = s1;
}

__global__ __launch_bounds__(256)
void finalize_kernel(const float* __restrict__ Part2, const float* __restrict__ b2_0,
                     const float* __restrict__ w2_1, const float* __restrict__ b2_1,
                     float* __restrict__ out) {
    __shared__ float red[256];
    const int tid = threadIdx.x;
    float result = 0.0f;
    for (int g = 0; g < 2; ++g) {
        float s = 0.f;
        for (int n = tid; n < 2048; n += 256) {
            float acc = b2_0[n];
            #pragma unroll
            for (int kc = 0; kc < 16; ++kc)
                acc += Part2[kc * 4096 + g * 2048 + n];
            s += tanhf(acc) * w2_1[n];
        }
        red[tid] = s;
        __syncthreads();
        for (int off = 128; off > 0; off >>= 1) {
            if (tid < off) red[tid] += red[tid + off];
            __syncthreads();
        }
        if (tid == 0) result += logf(fabsf(red[0] + b2_1[0]));
        __syncthreads();
    }
    if (tid == 0) out[0] = result;
}

extern "C" void kernel_launch(void* const* d_in, const int* in_sizes, int n_in,
                              void* d_out, int out_size, void* d_ws, size_t ws_size,
                              hipStream_t stream) {
    const float* h_one = (const float*)d_in[0];
    const float* w1_0  = (const float*)d_in[1];
    const float* b1_0  = (const float*)d_in[2];
    const float* w1_1  = (const float*)d_in[3];
    const float* b1_1  = (const float*)d_in[4];
    const float* w1_2  = (const float*)d_in[5];
    const float* b1_2  = (const float*)d_in[6];
    const float* w2_0  = (const float*)d_in[7];
    const float* b2_0  = (const float*)d_in[8];
    const float* w2_1  = (const float*)d_in[9];
    const float* b2_1  = (const float*)d_in[10];
    float* out = (float*)d_out;

    char* ws = (char*)d_ws;
    // region0: W10t (33.5 MB), later PartL1 (4 x 512 x 4096 f32)
    unsigned short* W10t_h = (unsigned short*)ws;
    unsigned short* W10t_l = W10t_h + (size_t)4096 * 2048;
    float*          PartL1 = (float*)ws;
    ws += (size_t)4096 * 2048 * 2 * 2;
    // region1: W11t (67 MB), later PartL2 (8 x 512 x 2048 f32)
    unsigned short* W11t_h = (unsigned short*)ws;
    unsigned short* W11t_l = W11t_h + (size_t)4096 * 4096;
    float*          PartL2 = (float*)ws;
    ws += (size_t)4096 * 4096 * 2 * 2;
    // region2: W12t (33.5 MB), live through L2
    unsigned short* W12t_h = (unsigned short*)ws;
    unsigned short* W12t_l = W12t_h + (size_t)2048 * 4096;
    ws += (size_t)2048 * 4096 * 2 * 2;
    // block-diagonal A for PQ gemm: [128][2048] hi + lo (1 MB)
    unsigned short* Ah  = (unsigned short*)ws;  ws += (size_t)128 * 2048 * 2;
    unsigned short* Al  = (unsigned short*)ws;  ws += (size_t)128 * 2048 * 2;
    float* PQ  = (float*)ws;                    ws += (size_t)4 * 128 * 4096 * 4;
    unsigned short* Y1h = (unsigned short*)ws;  ws += (size_t)512 * 4096 * 2;
    unsigned short* Y1l = (unsigned short*)ws;  ws += (size_t)512 * 4096 * 2;
    unsigned short* Y2h = (unsigned short*)ws;  ws += (size_t)512 * 4096 * 2;
    unsigned short* Y2l = (unsigned short*)ws;  ws += (size_t)512 * 4096 * 2;
    float* Hb    = (float*)ws;                  ws += (size_t)512 * 2048 * 4;
    float* a_part = (float*)ws;                 ws += (size_t)8 * 2048 * 4;
    float* Part2 = (float*)ws;                  ws += (size_t)16 * 2 * 2048 * 4;

    // weight transposes + A-build (incl. zeroing) — no memset needed
    transpose_split_all<<<8200, 256, 0, stream>>>(w1_0, w1_1, w1_2, h_one,
                                                  W10t_h, W10t_l, W11t_h, W11t_l,
                                                  W12t_h, W12t_l, Ah, Al);

    // PQ: one gemm128, M=128 (P rows 0..63, Q rows 64..127), N=4096, K=2048, Z=4
    gemm128<<<dim3(32, 1, 4), 256, 0, stream>>>(Ah, Al, W10t_h, W10t_l, 2048,
                                                PQ, 4096, 128, 512);
    build_y1_kernel<<<dim3(480, 4), 256, 0, stream>>>(PQ, b1_0, Y1h, Y1l);

    // L1: Y2 = silu(Y1 @ W1_1 + b1_1)  M=512 N=4096 K=4096, Z=4
    gemm128<<<dim3(32, 4, 4), 256, 0, stream>>>(Y1h, Y1l, W11t_h, W11t_l, 4096,
                                                PartL1, 4096, 512, 1024);
    reduce4_silu_split<<<2048, 256, 0, stream>>>(PartL1, b1_1, Y2h, Y2l);

    // L2: Hb = Y2 @ W1_2 + b1_2  M=512 N=2048 K=4096, Z=8
    gemm128<<<dim3(16, 4, 8), 256, 0, stream>>>(Y2h, Y2l, W12t_h, W12t_l, 4096,
                                                PartL2, 2048, 512, 512);
    reduce8_bias<<<1024, 256, 0, stream>>>(PartL2, b1_2, Hb);

    // tail (4 separate launches — measured cheaper than any cross-block sync)
    reduce_prod_kernel<<<dim3(8, 2, 4), 256, 0, stream>>>(Hb, a_part);
    mlp2_acc2_kernel<<<dim3(8, 16), 256, 0, stream>>>(a_part, w2_0, Part2);
    finalize_kernel<<<1, 256, 0, stream>>>(Part2, b2_0, w2_1, b2_1, out);
}